// Round 3
// baseline (852.999 us; speedup 1.0000x reference)
//
#include <hip/hip_runtime.h>
#include <hip/hip_bf16.h>

typedef __hip_bfloat16 bf16;
typedef __attribute__((ext_vector_type(8))) short short8;   // 8 bf16 frag
typedef __attribute__((ext_vector_type(4))) float floatx4;  // MFMA C/D frag

#define HDIM 128
#define NCANON 27

// ------------------------------------------------- dtype detect (bf16 vs f32)
__global__ void detect_kernel(const unsigned short* __restrict__ xraw, int* __restrict__ flag) {
  int j = threadIdx.x;                      // 64 threads
  unsigned short u = xraw[2 * j];           // even indices only
  int e = (u >> 7) & 0xFF;
  int ok = (u == 0) || (e >= 100 && e <= 140);
  unsigned long long m = __ballot(ok);
  if (j == 0) flag[0] = (__popcll(m) >= 48) ? 1 : 0;   // 1 = bf16 storage
}

struct CanonDesc {
  const void* src[NCANON];
  int prefix[NCANON + 1];
};

__global__ void canon_kernel(CanonDesc d, const int* __restrict__ flag,
                             bf16* __restrict__ out, int total) {
  int t = blockIdx.x * 256 + threadIdx.x;
  if (t >= total) return;
  int ti = 0;
  while (d.prefix[ti + 1] <= t) ti++;
  int off = t - d.prefix[ti];
  if (flag[0]) out[t] = ((const bf16*)d.src[ti])[off];
  else         out[t] = __float2bfloat16(((const float*)d.src[ti])[off]);
}

__global__ void emit_kernel(const bf16* __restrict__ canon_out, const int* __restrict__ flag,
                            void* __restrict__ d_out, int n) {
  int t = blockIdx.x * 256 + threadIdx.x;
  if (t >= n) return;
  if (flag[0]) ((bf16*)d_out)[t] = canon_out[t];
  else         ((float*)d_out)[t] = __bfloat162float(canon_out[t]);
}

// ---------------------------------------------------------------- CSR build
__global__ void hist_kernel(const int* __restrict__ dst, int* __restrict__ cnt, int E) {
  int e = blockIdx.x * 256 + threadIdx.x;
  if (e < E) atomicAdd(&cnt[dst[e]], 1);
}

__global__ void scan_kernel(const int* __restrict__ cnt, int* __restrict__ row_start, int n) {
  __shared__ int sh[1024];
  __shared__ int carry;
  int tid = threadIdx.x;
  if (tid == 0) carry = 0;
  __syncthreads();
  for (int base = 0; base < n; base += 1024) {
    int i = base + tid;
    int v = (i < n) ? cnt[i] : 0;
    sh[tid] = v;
    __syncthreads();
    for (int off = 1; off < 1024; off <<= 1) {
      int t = (tid >= off) ? sh[tid - off] : 0;
      __syncthreads();
      sh[tid] += t;
      __syncthreads();
    }
    int incl = sh[tid];
    if (i < n) row_start[i] = carry + incl - v;
    __syncthreads();
    if (tid == 1023) carry += incl;
    __syncthreads();
  }
  if (tid == 0) row_start[n] = carry;
}

__global__ void scatter_kernel(const int* __restrict__ dst, const int* __restrict__ row_start,
                               int* __restrict__ cursor, int* __restrict__ sorted, int E) {
  int e = blockIdx.x * 256 + threadIdx.x;
  if (e < E) {
    int d = dst[e];
    int pos = row_start[d] + atomicAdd(&cursor[d], 1);
    sorted[pos] = e;
  }
}

// ------------------------------------------------------------- aggregation
// wave-per-node: lane = (sub 0..3)*16 + chunk 0..15; each lane reads 16B chunks
// of every 4th incident edge row, then shfl-xor reduce across subs.
__global__ void aggregate_kernel(const bf16* __restrict__ h_edges, const int* __restrict__ row_start,
                                 const int* __restrict__ sorted, bf16* __restrict__ m_node, int n) {
  int node = blockIdx.x * 4 + (threadIdx.x >> 6);
  if (node >= n) return;
  int lane = threadIdx.x & 63;
  int chunk = lane & 15;
  int sub = lane >> 4;
  int s = row_start[node], e = row_start[node + 1];
  float acc[8];
  #pragma unroll
  for (int j = 0; j < 8; j++) acc[j] = 0.f;
  for (int p = s + sub; p < e; p += 4) {
    int eid = sorted[p];
    short8 v = *(const short8*)(h_edges + (size_t)eid * HDIM + chunk * 8);
    #pragma unroll
    for (int j = 0; j < 8; j++) {
      unsigned int u = ((unsigned int)(unsigned short)v[j]) << 16;
      acc[j] += __uint_as_float(u);
    }
  }
  #pragma unroll
  for (int j = 0; j < 8; j++) {
    acc[j] += __shfl_xor(acc[j], 16);
    acc[j] += __shfl_xor(acc[j], 32);
  }
  if (sub == 0) {
    short8 o;
    #pragma unroll
    for (int j = 0; j < 8; j++) o[j] = (short)(__bfloat16_as_ushort(__float2bfloat16(acc[j])));
    *(short8*)(m_node + (size_t)node * HDIM + chunk * 8) = o;
  }
}

// -------------------------------------------------------- typed enc / dec
__global__ void encode_kernel(const bf16* __restrict__ x, const bf16* __restrict__ pe,
                              const int* __restrict__ types,
                              const bf16* __restrict__ W1, const bf16* __restrict__ b1,
                              const bf16* __restrict__ W2, const bf16* __restrict__ b2,
                              bf16* __restrict__ h_nodes, int n) {
  int node = blockIdx.x;
  if (node >= n) return;
  int j = threadIdx.x;  // 128
  int t = types[node];
  __shared__ float z[14];
  __shared__ float hid[HDIM];
  if (j < 6) z[j] = __bfloat162float(x[(size_t)node * 6 + j]);
  else if (j < 14) z[j] = __bfloat162float(pe[(size_t)node * 8 + (j - 6)]);
  __syncthreads();
  float acc = __bfloat162float(b1[t * HDIM + j]);
  #pragma unroll
  for (int i = 0; i < 14; i++) acc += z[i] * __bfloat162float(W1[((size_t)t * 14 + i) * HDIM + j]);
  hid[j] = fmaxf(acc, 0.f);
  __syncthreads();
  float o = __bfloat162float(b2[t * HDIM + j]);
  for (int k = 0; k < HDIM; k++) o += hid[k] * __bfloat162float(W2[((size_t)t * HDIM + k) * HDIM + j]);
  h_nodes[(size_t)node * HDIM + j] = __float2bfloat16(o);
}

__global__ void decode_kernel(const bf16* __restrict__ h_nodes, const int* __restrict__ types,
                              const bf16* __restrict__ W1, const bf16* __restrict__ b1,
                              const bf16* __restrict__ W2, const bf16* __restrict__ b2,
                              bf16* __restrict__ out, int n) {
  int node = blockIdx.x;
  if (node >= n) return;
  int j = threadIdx.x;  // 128
  int t = types[node];
  __shared__ float z[HDIM];
  __shared__ float hid[HDIM];
  z[j] = __bfloat162float(h_nodes[(size_t)node * HDIM + j]);
  __syncthreads();
  float acc = __bfloat162float(b1[t * HDIM + j]);
  for (int k = 0; k < HDIM; k++) acc += z[k] * __bfloat162float(W1[((size_t)t * HDIM + k) * HDIM + j]);
  hid[j] = fmaxf(acc, 0.f);
  __syncthreads();
  if (j < 4) {
    float o = __bfloat162float(b2[t * 4 + j]);
    for (int k = 0; k < HDIM; k++) o += hid[k] * __bfloat162float(W2[((size_t)t * HDIM + k) * 4 + j]);
    out[(size_t)node * 4 + j] = __float2bfloat16(o);
  }
}

// -------------------------------------------------- weight pre-pack (B-frag order)
__global__ void pack_w(const bf16* __restrict__ W, bf16* __restrict__ out,
                       int Ksrc, int KS, int strideIn, int strideOut) {
  int idx = blockIdx.x * 256 + threadIdx.x;
  int total = 8 * KS * 64;
  if (idx >= total) return;
  int lane = idx & 63;
  int ks = (idx >> 6) % KS;
  int ct = idx / (64 * KS);
  const bf16* Ws = W + (size_t)blockIdx.y * strideIn;
  bf16* o = out + (size_t)blockIdx.y * strideOut + (size_t)idx * 8;
  int ncol = ct * 16 + (lane & 15);
  int kb = ks * 32 + ((lane >> 4) & 3) * 8;
  #pragma unroll
  for (int j = 0; j < 8; j++) {
    int k = kb + j;
    o[j] = (k < Ksrc) ? Ws[(size_t)k * HDIM + ncol] : __float2bfloat16(0.f);
  }
}

// -------------------------------------------------- generic fused 2-layer MLP (MFMA)
// out = [Z[RES_PART*128..] +] (ReLU(Z @ W1 + b1) @ W2 + b2)
// Hid (136/row) aliases into Zt at HID_OFF (region dead after GEMM1; residual
// part kept disjoint). BM rows/block, 256 threads (4 waves), wave owns 32 cols.
template<int NPARTS, int KS1, int RES_PART, int BM, int HID_OFF, bool ATTR4>
__global__ void __launch_bounds__(256) mlp2_kernel(
    const bf16* __restrict__ p0, const int* __restrict__ idx0,
    const bf16* __restrict__ p1, const int* __restrict__ idx1,
    const bf16* __restrict__ p2, const int* __restrict__ idx2,
    const bf16* __restrict__ W1p, const bf16* __restrict__ b1v,
    const bf16* __restrict__ W2p, const bf16* __restrict__ b2v,
    bf16* __restrict__ outp, int M) {
  constexpr int RT = BM / 16;
  constexpr int SK = NPARTS * 128 + 8;    // padded row stride (word-span odd -> conflict-free)

  __shared__ bf16 Zt[BM * SK];
  bf16* Hid = &Zt[HID_OFF];

  const int tid = threadIdx.x;
  const int lane = tid & 63;
  const int wave = tid >> 6;
  const int colq = lane & 15;
  const int quad = lane >> 4;
  const int row0 = blockIdx.x * BM;

  // ---- stage Z tile
  if (ATTR4) {
    for (int i = tid; i < BM * 4; i += 256) {   // only k 0..31 used (KS1==1)
      int row = i >> 2, seg = i & 3;
      int gr = row0 + row;
      uint4 val = {0u, 0u, 0u, 0u};
      if (seg == 0 && gr < M) {
        uint2 v = *(const uint2*)(p0 + (size_t)gr * 4);
        val.x = v.x; val.y = v.y;
      }
      *(uint4*)(&Zt[row * SK + seg * 8]) = val;
    }
  } else {
    for (int i = tid; i < BM * NPARTS * 16; i += 256) {
      int row = i / (NPARTS * 16);
      int rem = i - row * (NPARTS * 16);
      int part = rem >> 4, seg = rem & 15;
      int gr = row0 + row;
      uint4 val = {0u, 0u, 0u, 0u};
      if (gr < M) {
        const bf16* p = (part == 0) ? p0 : ((part == 1) ? p1 : p2);
        const int* ix = (part == 0) ? idx0 : ((part == 1) ? idx1 : idx2);
        int g = ix ? ix[gr] : gr;
        val = *(const uint4*)(p + (size_t)g * HDIM + seg * 8);
      }
      *(uint4*)(&Zt[row * SK + part * 128 + seg * 8]) = val;
    }
  }
  __syncthreads();

  // ---- GEMM1: Hidden = ReLU(Z @ W1 + b1)
  floatx4 acc[RT][2];
  #pragma unroll
  for (int rt = 0; rt < RT; rt++)
    #pragma unroll
    for (int c = 0; c < 2; c++) acc[rt][c] = (floatx4){0.f, 0.f, 0.f, 0.f};

  #pragma unroll
  for (int ks = 0; ks < KS1; ks++) {
    short8 bfr0 = *(const short8*)(W1p + (((size_t)(wave * 2 + 0) * KS1 + ks) * 64 + lane) * 8);
    short8 bfr1 = *(const short8*)(W1p + (((size_t)(wave * 2 + 1) * KS1 + ks) * 64 + lane) * 8);
    #pragma unroll
    for (int rt = 0; rt < RT; rt++) {
      short8 a = *(const short8*)(&Zt[(rt * 16 + colq) * SK + ks * 32 + quad * 8]);
      acc[rt][0] = __builtin_amdgcn_mfma_f32_16x16x32_bf16(a, bfr0, acc[rt][0], 0, 0, 0);
      acc[rt][1] = __builtin_amdgcn_mfma_f32_16x16x32_bf16(a, bfr1, acc[rt][1], 0, 0, 0);
    }
  }
  __syncthreads();   // everyone done READING Zt before Hid overwrites it

  // bias + ReLU -> Hid rows (A-layout for GEMM2)
  #pragma unroll
  for (int c = 0; c < 2; c++) {
    int col = wave * 32 + c * 16 + colq;
    float bv = __bfloat162float(b1v[col]);
    #pragma unroll
    for (int rt = 0; rt < RT; rt++)
      #pragma unroll
      for (int r = 0; r < 4; r++) {
        float v = acc[rt][c][r] + bv;
        Hid[(rt * 16 + quad * 4 + r) * SK + col] = __float2bfloat16(fmaxf(v, 0.f));
      }
  }
  __syncthreads();

  // ---- GEMM2: Out = Hidden @ W2 + b2 (+ residual from Zt)
  floatx4 acc2[RT][2];
  #pragma unroll
  for (int rt = 0; rt < RT; rt++)
    #pragma unroll
    for (int c = 0; c < 2; c++) acc2[rt][c] = (floatx4){0.f, 0.f, 0.f, 0.f};

  #pragma unroll
  for (int ks = 0; ks < 4; ks++) {
    short8 bfr0 = *(const short8*)(W2p + (((size_t)(wave * 2 + 0) * 4 + ks) * 64 + lane) * 8);
    short8 bfr1 = *(const short8*)(W2p + (((size_t)(wave * 2 + 1) * 4 + ks) * 64 + lane) * 8);
    #pragma unroll
    for (int rt = 0; rt < RT; rt++) {
      short8 a = *(const short8*)(&Hid[(rt * 16 + colq) * SK + ks * 32 + quad * 8]);
      acc2[rt][0] = __builtin_amdgcn_mfma_f32_16x16x32_bf16(a, bfr0, acc2[rt][0], 0, 0, 0);
      acc2[rt][1] = __builtin_amdgcn_mfma_f32_16x16x32_bf16(a, bfr1, acc2[rt][1], 0, 0, 0);
    }
  }

  #pragma unroll
  for (int c = 0; c < 2; c++) {
    int col = wave * 32 + c * 16 + colq;
    float bv = __bfloat162float(b2v[col]);
    #pragma unroll
    for (int rt = 0; rt < RT; rt++)
      #pragma unroll
      for (int r = 0; r < 4; r++) {
        int lrow = rt * 16 + quad * 4 + r;
        int grow = row0 + lrow;
        if (grow < M) {
          float v = acc2[rt][c][r] + bv;
          if constexpr (RES_PART >= 0)
            v += __bfloat162float(Zt[lrow * SK + RES_PART * 128 + col]);
          outp[(size_t)grow * HDIM + col] = __float2bfloat16(v);
        }
      }
  }
}

// ---------------------------------------------------------------- launcher
extern "C" void kernel_launch(void* const* d_in, const int* in_sizes, int n_in,
                              void* d_out, int out_size, void* d_ws, size_t ws_size,
                              hipStream_t stream) {
  const int* edge_index = (const int*)d_in[27];
  const int* node_types = (const int*)d_in[28];
  const int N = in_sizes[28];
  const int E = in_sizes[2] / 4;
  const int L = in_sizes[12] / HDIM;
  const int* srcI = edge_index;
  const int* dstI = edge_index + E;

  CanonDesc cd;
  int total = 0;
  for (int i = 0; i < NCANON; i++) { cd.src[i] = d_in[i]; cd.prefix[i] = total; total += in_sizes[i]; }
  cd.prefix[NCANON] = total;

  char* wsb = (char*)d_ws;
  size_t off = 0;
  auto alloc = [&](size_t bytes) -> void* {
    void* p = wsb + off;
    off += (bytes + 255) & ~(size_t)255;
    return p;
  };
  int*  flag      = (int*)alloc(256);
  bf16* arena     = (bf16*)alloc((size_t)total * 2);
  bf16* h_nodes   = (bf16*)alloc((size_t)N * HDIM * 2);
  bf16* h_edges   = (bf16*)alloc((size_t)E * HDIM * 2);
  bf16* m_node    = (bf16*)alloc((size_t)N * HDIM * 2);
  bf16* localb    = (bf16*)alloc((size_t)N * HDIM * 2);
  bf16* canon_out = (bf16*)alloc((size_t)out_size * 2);
  int* counts     = (int*)alloc((size_t)N * 4);
  int* cursor     = (int*)alloc((size_t)N * 4);
  int* row_start  = (int*)alloc((size_t)(N + 1) * 4);
  int* sorted     = (int*)alloc((size_t)E * 4);
  bf16* eeW1p = (bf16*)alloc(4096 * 2);          // KS=1
  bf16* eeW2p = (bf16*)alloc(16384 * 2);
  bf16* euW1p = (bf16*)alloc((size_t)L * 49152 * 2);
  bf16* euW2p = (bf16*)alloc((size_t)L * 16384 * 2);
  bf16* nuW1p = (bf16*)alloc((size_t)L * 32768 * 2);
  bf16* nuW2p = (bf16*)alloc((size_t)L * 16384 * 2);
  bf16* fuW1p = (bf16*)alloc((size_t)L * 16384 * 2);
  bf16* fuW2p = (bf16*)alloc((size_t)L * 16384 * 2);

  const bf16* cX     = arena + cd.prefix[0];
  const bf16* cPE    = arena + cd.prefix[1];
  const bf16* cEA    = arena + cd.prefix[2];
  const bf16* cEncW1 = arena + cd.prefix[3];
  const bf16* cEncB1 = arena + cd.prefix[4];
  const bf16* cEncW2 = arena + cd.prefix[5];
  const bf16* cEncB2 = arena + cd.prefix[6];
  const bf16* cEeW1  = arena + cd.prefix[7];
  const bf16* cEeB1  = arena + cd.prefix[8];
  const bf16* cEeW2  = arena + cd.prefix[9];
  const bf16* cEeB2  = arena + cd.prefix[10];
  const bf16* cEuW1  = arena + cd.prefix[11];
  const bf16* cEuB1  = arena + cd.prefix[12];
  const bf16* cEuW2  = arena + cd.prefix[13];
  const bf16* cEuB2  = arena + cd.prefix[14];
  const bf16* cNuW1  = arena + cd.prefix[15];
  const bf16* cNuB1  = arena + cd.prefix[16];
  const bf16* cNuW2  = arena + cd.prefix[17];
  const bf16* cNuB2  = arena + cd.prefix[18];
  const bf16* cFuW1  = arena + cd.prefix[19];
  const bf16* cFuB1  = arena + cd.prefix[20];
  const bf16* cFuW2  = arena + cd.prefix[21];
  const bf16* cFuB2  = arena + cd.prefix[22];
  const bf16* cDecW1 = arena + cd.prefix[23];
  const bf16* cDecB1 = arena + cd.prefix[24];
  const bf16* cDecW2 = arena + cd.prefix[25];
  const bf16* cDecB2 = arena + cd.prefix[26];

  detect_kernel<<<1, 64, 0, stream>>>((const unsigned short*)d_in[0], flag);
  canon_kernel<<<(total + 255) / 256, 256, 0, stream>>>(cd, flag, arena, total);

  hipMemsetAsync(counts, 0, (size_t)N * 4, stream);
  hipMemsetAsync(cursor, 0, (size_t)N * 4, stream);

  pack_w<<<dim3(2, 1), 256, 0, stream>>>(cEeW1, eeW1p, 4, 1, 0, 0);
  pack_w<<<dim3(8, 1), 256, 0, stream>>>(cEeW2, eeW2p, 128, 4, 0, 0);
  pack_w<<<dim3(24, L), 256, 0, stream>>>(cEuW1, euW1p, 384, 12, 384 * HDIM, 49152);
  pack_w<<<dim3(8, L), 256, 0, stream>>>(cEuW2, euW2p, 128, 4, HDIM * HDIM, 16384);
  pack_w<<<dim3(16, L), 256, 0, stream>>>(cNuW1, nuW1p, 256, 8, 256 * HDIM, 32768);
  pack_w<<<dim3(8, L), 256, 0, stream>>>(cNuW2, nuW2p, 128, 4, HDIM * HDIM, 16384);
  pack_w<<<dim3(8, L), 256, 0, stream>>>(cFuW1, fuW1p, 128, 4, HDIM * HDIM, 16384);
  pack_w<<<dim3(8, L), 256, 0, stream>>>(cFuW2, fuW2p, 128, 4, HDIM * HDIM, 16384);

  hist_kernel<<<(E + 255) / 256, 256, 0, stream>>>(dstI, counts, E);
  scan_kernel<<<1, 1024, 0, stream>>>(counts, row_start, N);
  scatter_kernel<<<(E + 255) / 256, 256, 0, stream>>>(dstI, row_start, cursor, sorted, E);

  encode_kernel<<<N, 128, 0, stream>>>(cX, cPE, node_types, cEncW1, cEncB1, cEncW2, cEncB2, h_nodes, N);

  int egrid64  = (E + 63) / 64;
  int egrid128 = (E + 127) / 128;
  int ngrid64  = (N + 63) / 64;
  int ngrid128 = (N + 127) / 128;

  // edge encoder: K1=32 (ED=4 zero-padded), BM=128
  mlp2_kernel<1, 1, -1, 128, 0, true><<<egrid128, 256, 0, stream>>>(
      cEA, nullptr, nullptr, nullptr, nullptr, nullptr,
      eeW1p, cEeB1, eeW2p, cEeB2, h_edges, E);

  for (int l = 0; l < L; l++) {
    // edge update: NPARTS=3, BM=64, Hid@0, residual part2 (h_edges)
    mlp2_kernel<3, 12, 2, 64, 0, false><<<egrid64, 256, 0, stream>>>(
        h_nodes, srcI, h_nodes, dstI, h_edges, nullptr,
        euW1p + (size_t)l * 49152, cEuB1 + l * HDIM,
        euW2p + (size_t)l * 16384, cEuB2 + l * HDIM, h_edges, E);
    aggregate_kernel<<<(N + 3) / 4, 256, 0, stream>>>(h_edges, row_start, sorted, m_node, N);
    // node update: NPARTS=2, BM=64, Hid@128 (part1 dead), residual part0 (h_nodes)
    mlp2_kernel<2, 8, 0, 64, 128, false><<<ngrid64, 256, 0, stream>>>(
        h_nodes, nullptr, m_node, nullptr, nullptr, nullptr,
        nuW1p + (size_t)l * 32768, cNuB1 + l * HDIM,
        nuW2p + (size_t)l * 16384, cNuB2 + l * HDIM, localb, N);
    // fusion: NPARTS=1, BM=128, Hid@0, no residual
    mlp2_kernel<1, 4, -1, 128, 0, false><<<ngrid128, 256, 0, stream>>>(
        localb, nullptr, nullptr, nullptr, nullptr, nullptr,
        fuW1p + (size_t)l * 16384, cFuB1 + l * HDIM,
        fuW2p + (size_t)l * 16384, cFuB2 + l * HDIM, h_nodes, N);
  }

  decode_kernel<<<N, 128, 0, stream>>>(h_nodes, node_types, cDecW1, cDecB1, cDecW2, cDecB2,
                                       canon_out, N);
  emit_kernel<<<(out_size + 255) / 256, 256, 0, stream>>>(canon_out, flag, d_out, out_size);
  (void)n_in; (void)ws_size;
}

// Round 4
// 668.924 us; speedup vs baseline: 1.2752x; 1.2752x over previous
//
#include <hip/hip_runtime.h>
#include <hip/hip_bf16.h>

typedef __hip_bfloat16 bf16;
typedef __attribute__((ext_vector_type(8))) short short8;   // 8 bf16 frag
typedef __attribute__((ext_vector_type(4))) float floatx4;  // MFMA C/D frag

#define HDIM 128
#define NCANON 27

// ------------------------------------------------- dtype detect (bf16 vs f32)
__global__ void detect_kernel(const unsigned short* __restrict__ xraw, int* __restrict__ flag) {
  int j = threadIdx.x;                      // 64 threads
  unsigned short u = xraw[2 * j];           // even indices only
  int e = (u >> 7) & 0xFF;
  int ok = (u == 0) || (e >= 100 && e <= 140);
  unsigned long long m = __ballot(ok);
  if (j == 0) flag[0] = (__popcll(m) >= 48) ? 1 : 0;   // 1 = bf16 storage
}

struct CanonDesc {
  const void* src[NCANON];
  int prefix[NCANON + 1];
};

__global__ void canon_kernel(CanonDesc d, const int* __restrict__ flag,
                             bf16* __restrict__ out, int total) {
  int t = blockIdx.x * 256 + threadIdx.x;
  if (t >= total) return;
  int ti = 0;
  while (d.prefix[ti + 1] <= t) ti++;
  int off = t - d.prefix[ti];
  if (flag[0]) out[t] = ((const bf16*)d.src[ti])[off];
  else         out[t] = __float2bfloat16(((const float*)d.src[ti])[off]);
}

__global__ void emit_kernel(const bf16* __restrict__ canon_out, const int* __restrict__ flag,
                            void* __restrict__ d_out, int n) {
  int t = blockIdx.x * 256 + threadIdx.x;
  if (t >= n) return;
  if (flag[0]) ((bf16*)d_out)[t] = canon_out[t];
  else         ((float*)d_out)[t] = __bfloat162float(canon_out[t]);
}

// ---------------------------------------------------------------- CSR build
__global__ void hist_kernel(const int* __restrict__ dst, int* __restrict__ cnt, int E) {
  int e = blockIdx.x * 256 + threadIdx.x;
  if (e < E) atomicAdd(&cnt[dst[e]], 1);
}

// 3-phase scan: block sums -> 1-wave scan of block sums -> per-block rescan
__global__ void scan1_kernel(const int* __restrict__ cnt, int* __restrict__ bsum, int n) {
  int tid = threadIdx.x, lane = tid & 63, wave = tid >> 6;
  int i = blockIdx.x * 256 + tid;
  int v = (i < n) ? cnt[i] : 0;
  #pragma unroll
  for (int d = 32; d; d >>= 1) v += __shfl_down(v, d);
  __shared__ int ws[4];
  if (lane == 0) ws[wave] = v;
  __syncthreads();
  if (tid == 0) bsum[blockIdx.x] = ws[0] + ws[1] + ws[2] + ws[3];
}

__global__ void scan2_kernel(int* __restrict__ bsum, int nb) {   // nb <= 128; 64 threads
  int lane = threadIdx.x;
  int a0 = (lane < nb) ? bsum[lane] : 0;
  int b0 = (64 + lane < nb) ? bsum[64 + lane] : 0;
  int a = a0, b = b0;
  #pragma unroll
  for (int d = 1; d < 64; d <<= 1) { int t = __shfl_up(a, d); if (lane >= d) a += t; }
  int totA = __shfl(a, 63);
  #pragma unroll
  for (int d = 1; d < 64; d <<= 1) { int t = __shfl_up(b, d); if (lane >= d) b += t; }
  int totB = __shfl(b, 63);
  if (lane < nb) bsum[lane] = a - a0;                       // exclusive
  if (64 + lane < nb) bsum[64 + lane] = b - b0 + totA;
  if (lane == 0) bsum[nb] = totA + totB;
}

__global__ void scan3_kernel(const int* __restrict__ cnt, const int* __restrict__ bsum,
                             int* __restrict__ row_start, int n, int nb) {
  __shared__ int sh[256];
  int tid = threadIdx.x;
  int i = blockIdx.x * 256 + tid;
  int v = (i < n) ? cnt[i] : 0;
  sh[tid] = v;
  __syncthreads();
  #pragma unroll
  for (int off = 1; off < 256; off <<= 1) {
    int t = (tid >= off) ? sh[tid - off] : 0;
    __syncthreads();
    sh[tid] += t;
    __syncthreads();
  }
  if (i < n) row_start[i] = bsum[blockIdx.x] + sh[tid] - v;
  if (blockIdx.x == 0 && tid == 0) row_start[n] = bsum[nb];
}

// scatter: CSR position for each edge; emit permuted src/dst and edge id
__global__ void scatter_kernel(const int* __restrict__ src, const int* __restrict__ dst,
                               const int* __restrict__ row_start, int* __restrict__ cursor,
                               int* __restrict__ sortedE, int* __restrict__ srcS,
                               int* __restrict__ dstS, int E) {
  int e = blockIdx.x * 256 + threadIdx.x;
  if (e < E) {
    int d = dst[e];
    int pos = row_start[d] + atomicAdd(&cursor[d], 1);
    sortedE[pos] = e;
    srcS[pos] = src[e];
    dstS[pos] = d;
  }
}

// ------------------------------------------------------------- aggregation
// h_edges is dst-sorted: node's edges are rows [row_start[n], row_start[n+1]).
// wave-per-node, each iteration the wave reads 4 contiguous rows (1 KB).
__global__ void aggregate_kernel(const bf16* __restrict__ h_edges, const int* __restrict__ row_start,
                                 bf16* __restrict__ m_node, int n) {
  int node = blockIdx.x * 4 + (threadIdx.x >> 6);
  if (node >= n) return;
  int lane = threadIdx.x & 63;
  int chunk = lane & 15;
  int sub = lane >> 4;
  int s = row_start[node], e = row_start[node + 1];
  float acc[8];
  #pragma unroll
  for (int j = 0; j < 8; j++) acc[j] = 0.f;
  for (int p = s + sub; p < e; p += 4) {
    short8 v = *(const short8*)(h_edges + (size_t)p * HDIM + chunk * 8);
    #pragma unroll
    for (int j = 0; j < 8; j++) {
      unsigned int u = ((unsigned int)(unsigned short)v[j]) << 16;
      acc[j] += __uint_as_float(u);
    }
  }
  #pragma unroll
  for (int j = 0; j < 8; j++) {
    acc[j] += __shfl_xor(acc[j], 16);
    acc[j] += __shfl_xor(acc[j], 32);
  }
  if (sub == 0) {
    short8 o;
    #pragma unroll
    for (int j = 0; j < 8; j++) o[j] = (short)(__bfloat16_as_ushort(__float2bfloat16(acc[j])));
    *(short8*)(m_node + (size_t)node * HDIM + chunk * 8) = o;
  }
}

// -------------------------------------------------------- typed enc / dec
__global__ void encode_kernel(const bf16* __restrict__ x, const bf16* __restrict__ pe,
                              const int* __restrict__ types,
                              const bf16* __restrict__ W1, const bf16* __restrict__ b1,
                              const bf16* __restrict__ W2, const bf16* __restrict__ b2,
                              bf16* __restrict__ h_nodes, int n) {
  int node = blockIdx.x;
  if (node >= n) return;
  int j = threadIdx.x;  // 128
  int t = types[node];
  __shared__ float z[14];
  __shared__ float hid[HDIM];
  if (j < 6) z[j] = __bfloat162float(x[(size_t)node * 6 + j]);
  else if (j < 14) z[j] = __bfloat162float(pe[(size_t)node * 8 + (j - 6)]);
  __syncthreads();
  float acc = __bfloat162float(b1[t * HDIM + j]);
  #pragma unroll
  for (int i = 0; i < 14; i++) acc += z[i] * __bfloat162float(W1[((size_t)t * 14 + i) * HDIM + j]);
  hid[j] = fmaxf(acc, 0.f);
  __syncthreads();
  float o = __bfloat162float(b2[t * HDIM + j]);
  for (int k = 0; k < HDIM; k++) o += hid[k] * __bfloat162float(W2[((size_t)t * HDIM + k) * HDIM + j]);
  h_nodes[(size_t)node * HDIM + j] = __float2bfloat16(o);
}

__global__ void decode_kernel(const bf16* __restrict__ h_nodes, const int* __restrict__ types,
                              const bf16* __restrict__ W1, const bf16* __restrict__ b1,
                              const bf16* __restrict__ W2, const bf16* __restrict__ b2,
                              bf16* __restrict__ out, int n) {
  int node = blockIdx.x;
  if (node >= n) return;
  int j = threadIdx.x;  // 128
  int t = types[node];
  __shared__ float z[HDIM];
  __shared__ float hid[HDIM];
  z[j] = __bfloat162float(h_nodes[(size_t)node * HDIM + j]);
  __syncthreads();
  float acc = __bfloat162float(b1[t * HDIM + j]);
  for (int k = 0; k < HDIM; k++) acc += z[k] * __bfloat162float(W1[((size_t)t * HDIM + k) * HDIM + j]);
  hid[j] = fmaxf(acc, 0.f);
  __syncthreads();
  if (j < 4) {
    float o = __bfloat162float(b2[t * 4 + j]);
    for (int k = 0; k < HDIM; k++) o += hid[k] * __bfloat162float(W2[((size_t)t * HDIM + k) * 4 + j]);
    out[(size_t)node * 4 + j] = __float2bfloat16(o);
  }
}

// -------------------------------------------------- fused weight pre-pack (B-frag order)
struct PackJob { const bf16* src; bf16* dst; int Ksrc; int KS; };
struct PackJobs { PackJob j[20]; };

__global__ void pack_all_kernel(PackJobs J) {
  PackJob job = J.j[blockIdx.y];
  int idx = blockIdx.x * 256 + threadIdx.x;
  int total = 8 * job.KS * 64;
  if (idx >= total) return;
  int lane = idx & 63;
  int ks = (idx >> 6) % job.KS;
  int ct = idx / (64 * job.KS);
  bf16* o = job.dst + (size_t)idx * 8;
  int ncol = ct * 16 + (lane & 15);
  int kb = ks * 32 + ((lane >> 4) & 3) * 8;
  #pragma unroll
  for (int jj = 0; jj < 8; jj++) {
    int k = kb + jj;
    o[jj] = (k < job.Ksrc) ? job.src[(size_t)k * HDIM + ncol] : __float2bfloat16(0.f);
  }
}

// -------------------------------------------------- generic fused 2-layer MLP (MFMA)
// out = [Z[RES_PART*128..] +] (ReLU(Z @ W1 + b1) @ W2 + b2)
// Hid aliases into Zt at HID_OFF (region dead after GEMM1; residual part disjoint).
// BM rows/block, 256 threads (4 waves), wave owns a 32-col output strip.
template<int NPARTS, int KS1, int RES_PART, int BM, int HID_OFF, bool ATTR4>
__global__ void __launch_bounds__(256) mlp2_kernel(
    const bf16* __restrict__ p0, const int* __restrict__ idx0,
    const bf16* __restrict__ p1, const int* __restrict__ idx1,
    const bf16* __restrict__ p2,
    const bf16* __restrict__ W1p, const bf16* __restrict__ b1v,
    const bf16* __restrict__ W2p, const bf16* __restrict__ b2v,
    bf16* __restrict__ outp, int M) {
  constexpr int RT = BM / 16;
  constexpr int SK = NPARTS * 128 + 8;    // padded row stride

  __shared__ bf16 Zt[BM * SK];
  bf16* Hid = &Zt[HID_OFF];

  const int tid = threadIdx.x;
  const int lane = tid & 63;
  const int wave = tid >> 6;
  const int colq = lane & 15;
  const int quad = lane >> 4;
  const int row0 = blockIdx.x * BM;

  // ---- stage Z tile: thread owns one row; indices loaded up front, then
  // independent uint4 loads (ILP).
  if (ATTR4) {
    for (int i = tid; i < BM * 4; i += 256) {   // KS1==1: only k 0..31 staged
      int row = i >> 2, seg = i & 3;
      int gr = row0 + row;
      uint4 val = {0u, 0u, 0u, 0u};
      if (seg == 0 && gr < M) {
        int g = idx0 ? idx0[gr] : gr;
        uint2 v = *(const uint2*)(p0 + (size_t)g * 4);
        val.x = v.x; val.y = v.y;
      }
      *(uint4*)(&Zt[row * SK + seg * 8]) = val;
    }
  } else {
    constexpr int TPR = 256 / BM;           // threads per row
    constexpr int PT = NPARTS * 16 / TPR;   // uint4s per thread
    int row = tid / TPR;
    int sub = tid % TPR;
    int gr = row0 + row;
    bool ok = (gr < M);
    int g0 = (idx0 && ok) ? idx0[gr] : gr;
    int g1 = (idx1 && ok) ? idx1[gr] : gr;
    #pragma unroll
    for (int j = 0; j < PT; j++) {
      int c = j * TPR + sub;
      int part = c >> 4, seg = c & 15;
      uint4 val = {0u, 0u, 0u, 0u};
      if (ok) {
        const bf16* p = (part == 0) ? p0 : ((part == 1) ? p1 : p2);
        int g = (part == 0) ? g0 : ((part == 1) ? g1 : gr);
        val = *(const uint4*)(p + (size_t)g * HDIM + seg * 8);
      }
      *(uint4*)(&Zt[row * SK + part * 128 + seg * 8]) = val;
    }
  }
  __syncthreads();

  // ---- GEMM1: Hidden = ReLU(Z @ W1 + b1)
  floatx4 acc[RT][2];
  #pragma unroll
  for (int rt = 0; rt < RT; rt++)
    #pragma unroll
    for (int c = 0; c < 2; c++) acc[rt][c] = (floatx4){0.f, 0.f, 0.f, 0.f};

  #pragma unroll
  for (int ks = 0; ks < KS1; ks++) {
    short8 bfr0 = *(const short8*)(W1p + (((size_t)(wave * 2 + 0) * KS1 + ks) * 64 + lane) * 8);
    short8 bfr1 = *(const short8*)(W1p + (((size_t)(wave * 2 + 1) * KS1 + ks) * 64 + lane) * 8);
    #pragma unroll
    for (int rt = 0; rt < RT; rt++) {
      short8 a = *(const short8*)(&Zt[(rt * 16 + colq) * SK + ks * 32 + quad * 8]);
      acc[rt][0] = __builtin_amdgcn_mfma_f32_16x16x32_bf16(a, bfr0, acc[rt][0], 0, 0, 0);
      acc[rt][1] = __builtin_amdgcn_mfma_f32_16x16x32_bf16(a, bfr1, acc[rt][1], 0, 0, 0);
    }
  }
  __syncthreads();   // everyone done READING Zt before Hid overwrites it

  // bias + ReLU -> Hid rows (A-layout for GEMM2)
  #pragma unroll
  for (int c = 0; c < 2; c++) {
    int col = wave * 32 + c * 16 + colq;
    float bv = __bfloat162float(b1v[col]);
    #pragma unroll
    for (int rt = 0; rt < RT; rt++)
      #pragma unroll
      for (int r = 0; r < 4; r++) {
        float v = acc[rt][c][r] + bv;
        Hid[(rt * 16 + quad * 4 + r) * SK + col] = __float2bfloat16(fmaxf(v, 0.f));
      }
  }
  __syncthreads();

  // ---- GEMM2: Out = Hidden @ W2 + b2 (+ residual from Zt)
  floatx4 acc2[RT][2];
  #pragma unroll
  for (int rt = 0; rt < RT; rt++)
    #pragma unroll
    for (int c = 0; c < 2; c++) acc2[rt][c] = (floatx4){0.f, 0.f, 0.f, 0.f};

  #pragma unroll
  for (int ks = 0; ks < 4; ks++) {
    short8 bfr0 = *(const short8*)(W2p + (((size_t)(wave * 2 + 0) * 4 + ks) * 64 + lane) * 8);
    short8 bfr1 = *(const short8*)(W2p + (((size_t)(wave * 2 + 1) * 4 + ks) * 64 + lane) * 8);
    #pragma unroll
    for (int rt = 0; rt < RT; rt++) {
      short8 a = *(const short8*)(&Hid[(rt * 16 + colq) * SK + ks * 32 + quad * 8]);
      acc2[rt][0] = __builtin_amdgcn_mfma_f32_16x16x32_bf16(a, bfr0, acc2[rt][0], 0, 0, 0);
      acc2[rt][1] = __builtin_amdgcn_mfma_f32_16x16x32_bf16(a, bfr1, acc2[rt][1], 0, 0, 0);
    }
  }

  #pragma unroll
  for (int c = 0; c < 2; c++) {
    int col = wave * 32 + c * 16 + colq;
    float bv = __bfloat162float(b2v[col]);
    #pragma unroll
    for (int rt = 0; rt < RT; rt++)
      #pragma unroll
      for (int r = 0; r < 4; r++) {
        int lrow = rt * 16 + quad * 4 + r;
        int grow = row0 + lrow;
        if (grow < M) {
          float v = acc2[rt][c][r] + bv;
          if constexpr (RES_PART >= 0)
            v += __bfloat162float(Zt[lrow * SK + RES_PART * 128 + col]);
          outp[(size_t)grow * HDIM + col] = __float2bfloat16(v);
        }
      }
  }
}

// ---------------------------------------------------------------- launcher
extern "C" void kernel_launch(void* const* d_in, const int* in_sizes, int n_in,
                              void* d_out, int out_size, void* d_ws, size_t ws_size,
                              hipStream_t stream) {
  const int* edge_index = (const int*)d_in[27];
  const int* node_types = (const int*)d_in[28];
  const int N = in_sizes[28];
  const int E = in_sizes[2] / 4;
  const int L = in_sizes[12] / HDIM;
  const int* srcI = edge_index;
  const int* dstI = edge_index + E;

  CanonDesc cd;
  int total = 0;
  for (int i = 0; i < NCANON; i++) { cd.src[i] = d_in[i]; cd.prefix[i] = total; total += in_sizes[i]; }
  cd.prefix[NCANON] = total;

  char* wsb = (char*)d_ws;
  size_t off = 0;
  auto alloc = [&](size_t bytes) -> void* {
    void* p = wsb + off;
    off += (bytes + 255) & ~(size_t)255;
    return p;
  };
  int*  flag      = (int*)alloc(256);
  bf16* arena     = (bf16*)alloc((size_t)total * 2);
  bf16* h_nodes   = (bf16*)alloc((size_t)N * HDIM * 2);
  bf16* h_edges   = (bf16*)alloc((size_t)E * HDIM * 2);
  bf16* m_node    = (bf16*)alloc((size_t)N * HDIM * 2);
  bf16* localb    = (bf16*)alloc((size_t)N * HDIM * 2);
  bf16* canon_out = (bf16*)alloc((size_t)out_size * 2);
  int* counts     = (int*)alloc((size_t)N * 4);
  int* cursor     = (int*)alloc((size_t)N * 4);
  int* row_start  = (int*)alloc((size_t)(N + 1) * 4);
  int* bsum       = (int*)alloc(260 * 4);
  int* sortedE    = (int*)alloc((size_t)E * 4);
  int* srcS       = (int*)alloc((size_t)E * 4);
  int* dstS       = (int*)alloc((size_t)E * 4);
  bf16* eeW1p = (bf16*)alloc(4096 * 2);          // KS=1
  bf16* eeW2p = (bf16*)alloc(16384 * 2);
  bf16* euW1p = (bf16*)alloc((size_t)L * 49152 * 2);
  bf16* euW2p = (bf16*)alloc((size_t)L * 16384 * 2);
  bf16* nuW1p = (bf16*)alloc((size_t)L * 32768 * 2);
  bf16* nuW2p = (bf16*)alloc((size_t)L * 16384 * 2);
  bf16* fuW1p = (bf16*)alloc((size_t)L * 16384 * 2);
  bf16* fuW2p = (bf16*)alloc((size_t)L * 16384 * 2);

  const bf16* cX     = arena + cd.prefix[0];
  const bf16* cPE    = arena + cd.prefix[1];
  const bf16* cEA    = arena + cd.prefix[2];
  const bf16* cEncW1 = arena + cd.prefix[3];
  const bf16* cEncB1 = arena + cd.prefix[4];
  const bf16* cEncW2 = arena + cd.prefix[5];
  const bf16* cEncB2 = arena + cd.prefix[6];
  const bf16* cEeW1  = arena + cd.prefix[7];
  const bf16* cEeB1  = arena + cd.prefix[8];
  const bf16* cEeW2  = arena + cd.prefix[9];
  const bf16* cEeB2  = arena + cd.prefix[10];
  const bf16* cEuW1  = arena + cd.prefix[11];
  const bf16* cEuB1  = arena + cd.prefix[12];
  const bf16* cEuW2  = arena + cd.prefix[13];
  const bf16* cEuB2  = arena + cd.prefix[14];
  const bf16* cNuW1  = arena + cd.prefix[15];
  const bf16* cNuB1  = arena + cd.prefix[16];
  const bf16* cNuW2  = arena + cd.prefix[17];
  const bf16* cNuB2  = arena + cd.prefix[18];
  const bf16* cFuW1  = arena + cd.prefix[19];
  const bf16* cFuB1  = arena + cd.prefix[20];
  const bf16* cFuW2  = arena + cd.prefix[21];
  const bf16* cFuB2  = arena + cd.prefix[22];
  const bf16* cDecW1 = arena + cd.prefix[23];
  const bf16* cDecB1 = arena + cd.prefix[24];
  const bf16* cDecW2 = arena + cd.prefix[25];
  const bf16* cDecB2 = arena + cd.prefix[26];

  detect_kernel<<<1, 64, 0, stream>>>((const unsigned short*)d_in[0], flag);
  canon_kernel<<<(total + 255) / 256, 256, 0, stream>>>(cd, flag, arena, total);

  hipMemsetAsync(counts, 0, (size_t)N * 4, stream);
  hipMemsetAsync(cursor, 0, (size_t)N * 4, stream);

  // fused weight packing (one dispatch)
  PackJobs PJ;
  int nj = 0;
  PJ.j[nj++] = {cEeW1, eeW1p, 4, 1};
  PJ.j[nj++] = {cEeW2, eeW2p, 128, 4};
  for (int l = 0; l < L; l++) {
    PJ.j[nj++] = {cEuW1 + (size_t)l * 384 * HDIM, euW1p + (size_t)l * 49152, 384, 12};
    PJ.j[nj++] = {cEuW2 + (size_t)l * HDIM * HDIM, euW2p + (size_t)l * 16384, 128, 4};
    PJ.j[nj++] = {cNuW1 + (size_t)l * 256 * HDIM, nuW1p + (size_t)l * 32768, 256, 8};
    PJ.j[nj++] = {cNuW2 + (size_t)l * HDIM * HDIM, nuW2p + (size_t)l * 16384, 128, 4};
    PJ.j[nj++] = {cFuW1 + (size_t)l * HDIM * HDIM, fuW1p + (size_t)l * 16384, 128, 4};
    PJ.j[nj++] = {cFuW2 + (size_t)l * HDIM * HDIM, fuW2p + (size_t)l * 16384, 128, 4};
  }
  pack_all_kernel<<<dim3(24, nj), 256, 0, stream>>>(PJ);

  // CSR build (3-phase scan)
  int nb = (N + 255) / 256;
  hist_kernel<<<(E + 255) / 256, 256, 0, stream>>>(dstI, counts, E);
  scan1_kernel<<<nb, 256, 0, stream>>>(counts, bsum, N);
  scan2_kernel<<<1, 64, 0, stream>>>(bsum, nb);
  scan3_kernel<<<nb, 256, 0, stream>>>(counts, bsum, row_start, N, nb);
  scatter_kernel<<<(E + 255) / 256, 256, 0, stream>>>(srcI, dstI, row_start, cursor,
                                                      sortedE, srcS, dstS, E);

  encode_kernel<<<N, 128, 0, stream>>>(cX, cPE, node_types, cEncW1, cEncB1, cEncW2, cEncB2, h_nodes, N);

  int egrid32  = (E + 31) / 32;
  int egrid128 = (E + 127) / 128;
  int ngrid64  = (N + 63) / 64;
  int ngrid128 = (N + 127) / 128;

  // edge encoder: gathers edge_attr via sortedE -> h_edges in dst-sorted order
  mlp2_kernel<1, 1, -1, 128, 0, true><<<egrid128, 256, 0, stream>>>(
      cEA, sortedE, nullptr, nullptr, nullptr,
      eeW1p, cEeB1, eeW2p, cEeB2, h_edges, E);

  for (int l = 0; l < L; l++) {
    // edge update (sorted order): BM=32, Hid aliased @0, residual part2; 25 KB LDS -> 6 blk/CU
    mlp2_kernel<3, 12, 2, 32, 0, false><<<egrid32, 256, 0, stream>>>(
        h_nodes, srcS, h_nodes, dstS, h_edges,
        euW1p + (size_t)l * 49152, cEuB1 + l * HDIM,
        euW2p + (size_t)l * 16384, cEuB2 + l * HDIM, h_edges, E);
    // sequential segmented sum over sorted h_edges
    aggregate_kernel<<<(N + 3) / 4, 256, 0, stream>>>(h_edges, row_start, m_node, N);
    // node update: BM=64, Hid @128 (part1 dead), residual part0
    mlp2_kernel<2, 8, 0, 64, 128, false><<<ngrid64, 256, 0, stream>>>(
        h_nodes, nullptr, m_node, nullptr, nullptr,
        nuW1p + (size_t)l * 32768, cNuB1 + l * HDIM,
        nuW2p + (size_t)l * 16384, cNuB2 + l * HDIM, localb, N);
    // fusion: BM=128, Hid @0
    mlp2_kernel<1, 4, -1, 128, 0, false><<<ngrid128, 256, 0, stream>>>(
        localb, nullptr, nullptr, nullptr, nullptr,
        fuW1p + (size_t)l * 16384, cFuB1 + l * HDIM,
        fuW2p + (size_t)l * 16384, cFuB2 + l * HDIM, h_nodes, N);
  }

  decode_kernel<<<N, 128, 0, stream>>>(h_nodes, node_types, cDecW1, cDecB1, cDecW2, cDecB2,
                                       canon_out, N);
  emit_kernel<<<(out_size + 255) / 256, 256, 0, stream>>>(canon_out, flag, d_out, out_size);
  (void)n_in; (void)ws_size;
}